// Round 1
// baseline (15.834 us; speedup 1.0000x reference)
//
#include <hip/hip_runtime.h>

// EmbeddingShardV2: out[b,s,:] = W[x[b,s],:] + bias
// x: [4,2048] int32, W: [50304,1024] f32, b: [1024] f32, out: [4,2048,1024] f32
// Pure memory-bound gather: 1 float4 load + 1 float4 bias load (cached) +
// 1 float4 store per lane. One 256-thread block per token (D=1024 -> 256 float4).

constexpr int D4 = 1024 / 4;  // float4s per row

__global__ __launch_bounds__(256)
void embed_gather_kernel(const int* __restrict__ x,
                         const float4* __restrict__ W,
                         const float4* __restrict__ bias,
                         float4* __restrict__ out,
                         int n_tok) {
    const int t = blockIdx.x;
    if (t >= n_tok) return;
    const int row = x[t];                      // broadcast load (same addr all lanes)
    const float4* __restrict__ src = W + (size_t)row * D4;
    float4* __restrict__ dst = out + (size_t)t * D4;
    const int i = threadIdx.x;                 // 0..255 == D4
    float4 w = src[i];
    float4 bb = bias[i];                       // L1/L2-resident after first blocks
    w.x += bb.x; w.y += bb.y; w.z += bb.z; w.w += bb.w;
    dst[i] = w;
}

extern "C" void kernel_launch(void* const* d_in, const int* in_sizes, int n_in,
                              void* d_out, int out_size, void* d_ws, size_t ws_size,
                              hipStream_t stream) {
    const int*    x    = (const int*)d_in[0];     // [B*S] = 8192
    const float4* W    = (const float4*)d_in[1];  // [50304,1024] f32
    const float4* bias = (const float4*)d_in[2];  // [1024] f32
    float4*       out  = (float4*)d_out;          // [B*S,1024] f32

    const int n_tok = in_sizes[0];                // 8192
    embed_gather_kernel<<<n_tok, 256, 0, stream>>>(x, W, bias, out, n_tok);
}